// Round 17
// baseline (194.199 us; speedup 1.0000x reference)
//
#include <hip/hip_runtime.h>
#include <stdint.h>

// BinarizeLinear inference: out = sign(X) @ sign(W) + bias
// Round 15 (resubmit x2): counted-vmcnt staging pipeline (the m218 lever).
// 3-deep LDS buffers (72 KiB, 2 blocks/CU): stage t+2 issued at step t,
// vmcnt(6) waits only step-t's loads -- step-t+1's stay in flight ACROSS
// the barrier. No per-step vmcnt(0) drain. Tile/layout as round 14
// (256x128, 4 waves, BK=64, [kt][p][g] blocked operands). Exact int math.

#define N_ROWS 8192
#define K_DIM  4096
#define O_DIM  4096
#define KW     64

typedef int int4v  __attribute__((ext_vector_type(4)));
typedef int int16v __attribute__((ext_vector_type(16)));

// ====================== X -> fragment-blocked i8 ([G][kt][p][g]) ============
__global__ __launch_bounds__(256) void convert_x_kernel(
        const float* __restrict__ X, int8_t* __restrict__ XBlk) {
    int u    = blockIdx.x * 4 + (threadIdx.x >> 6);   // piece id, [0, 32768)
    int lane = threadIdx.x & 63;
    int g = u & 7, p = (u >> 3) & 3, kt = (u >> 5) & 31, G = u >> 10;
    int n    = G * 256 + g * 32 + (lane & 31);
    int kcol = kt * 128 + p * 32 + (lane >> 5) * 16;
    const float4* src = (const float4*)(X + (size_t)n * K_DIM + kcol);
    uint32_t ow[4];
    #pragma unroll
    for (int q = 0; q < 4; ++q) {
        float4 v = src[q];
        uint32_t b0 = v.x > 0.0f ? 0x01u : 0xFFu;
        uint32_t b1 = v.y > 0.0f ? 0x01u : 0xFFu;
        uint32_t b2 = v.z > 0.0f ? 0x01u : 0xFFu;
        uint32_t b3 = v.w > 0.0f ? 0x01u : 0xFFu;
        ow[q] = b0 | (b1 << 8) | (b2 << 16) | (b3 << 24);
    }
    int4v o; o.x = ow[0]; o.y = ow[1]; o.z = ow[2]; o.w = ow[3];
    *(int4v*)(XBlk + (size_t)u * 1024 + lane * 16) = o;
}

// ====================== W (f32 [in][out]) -> blocked i8 ([G][kt][p][g]) =====
__global__ __launch_bounds__(256) void convert_w_kernel(
        const float* __restrict__ W, int8_t* __restrict__ WBlk) {
    int u    = blockIdx.x * 4 + (threadIdx.x >> 6);   // piece id, [0, 16384)
    int lane = threadIdx.x & 63;
    int g = u & 7, p = (u >> 3) & 3, kt = (u >> 5) & 31, G = u >> 10;
    int o     = G * 256 + g * 32 + (lane & 31);
    int kbase = kt * 128 + p * 32 + (lane >> 5) * 16;
    const float* src = W + (size_t)kbase * O_DIM + o;
    uint32_t ow[4];
    #pragma unroll
    for (int q = 0; q < 4; ++q) {
        uint32_t v = 0;
        #pragma unroll
        for (int b = 0; b < 4; ++b) {
            float f = src[(size_t)(q * 4 + b) * O_DIM];
            v |= (f > 0.0f ? 0x01u : 0xFFu) << (8 * b);
        }
        ow[q] = v;
    }
    int4v ov; ov.x = ow[0]; ov.y = ow[1]; ov.z = ow[2]; ov.w = ow[3];
    *(int4v*)(WBlk + (size_t)u * 1024 + lane * 16) = ov;
}

// ====================== 256x128 i8 GEMM, 3-deep counted pipeline ============
// Grid 1024 (32M x 32N), 256 thr / 4 waves, per-wave 128x64 (4x2 of 32x32).
// BK=64 (2 phases/step, 64 steps). LDS 3 x [A 16KB | B 8KB] = 72 KiB.
__global__ __launch_bounds__(256, 2) void i8_gemm256_kernel(
        const int8_t* __restrict__ XBlk, const int8_t* __restrict__ WBlk,
        const float* __restrict__ bias, float* __restrict__ out) {
    __shared__ int8_t lds[3 * 24576];    // 72 KiB

    const int tid  = threadIdx.x;
    const int swzb = (blockIdx.x & 7) * 128 + (blockIdx.x >> 3);  // XCD swizzle
    const int brow = (swzb >> 5) * 256;
    const int bcol = (swzb & 31) * 128;

    const int lane = tid & 63;
    const int wid  = tid >> 6;
    const int wrow = (wid >> 1) * 128;   // 2 M-groups
    const int wcol = (wid & 1) * 64;     // 2 N-groups
    const int l31  = lane & 31;
    const int lh   = lane >> 5;

    const int ag0 = (wrow >> 5) * 1024;  // 0 or 4096
    const int bg0 = (wcol >> 5) * 1024;  // 0 or 2048

    const int8_t* Asrc = XBlk + ((size_t)(brow >> 8) << 20) + tid * 16;
    const int8_t* Bsrc = WBlk + ((size_t)(bcol >> 8) << 20)
                              + ((bcol & 255) >> 5) * 1024 + tid * 16;

#define GSTAGE(buf, t)                                                        \
    {                                                                         \
        const int kt_  = (t) >> 1;                                            \
        const int ph2_ = ((t) & 1) * 2;                                       \
        _Pragma("unroll")                                                     \
        for (int j = 0; j < 4; ++j) {                                         \
            __builtin_amdgcn_global_load_lds(                                 \
                (const __attribute__((address_space(1))) void*)               \
                    (Asrc + (size_t)kt_ * 32768 + ph2_ * 8192 + j * 4096),    \
                (__attribute__((address_space(3))) void*)                     \
                    (lds + (buf) * 24576 + j * 4096 + tid * 16), 16, 0, 0);   \
        }                                                                     \
        _Pragma("unroll")                                                     \
        for (int j = 0; j < 2; ++j) {                                         \
            __builtin_amdgcn_global_load_lds(                                 \
                (const __attribute__((address_space(1))) void*)               \
                    (Bsrc + (size_t)kt_ * 32768 + (ph2_ + j) * 8192),         \
                (__attribute__((address_space(3))) void*)                     \
                    (lds + (buf) * 24576 + 16384 + j * 4096 + tid * 16),      \
                16, 0, 0);                                                    \
        }                                                                     \
    }

#define LOADP(A0, A1, A2, A3, B0, B1, buf, pp)                                \
    {                                                                         \
        const int8_t* Ap = lds + (buf) * 24576 + (pp) * 8192 + ag0 + lane*16; \
        const int8_t* Bp = lds + (buf) * 24576 + 16384 + (pp) * 4096 + bg0    \
                           + lane * 16;                                       \
        A0 = *(const int4v*)(Ap);                                             \
        A1 = *(const int4v*)(Ap + 1024);                                      \
        A2 = *(const int4v*)(Ap + 2048);                                      \
        A3 = *(const int4v*)(Ap + 3072);                                      \
        B0 = *(const int4v*)(Bp);                                             \
        B1 = *(const int4v*)(Bp + 1024);                                      \
    }

#define MFMA8(A0, A1, A2, A3, B0, B1)                                         \
    {                                                                         \
        __builtin_amdgcn_s_setprio(1);                                        \
        c00 = __builtin_amdgcn_mfma_i32_32x32x32_i8(A0, B0, c00, 0, 0, 0);    \
        c01 = __builtin_amdgcn_mfma_i32_32x32x32_i8(A0, B1, c01, 0, 0, 0);    \
        c10 = __builtin_amdgcn_mfma_i32_32x32x32_i8(A1, B0, c10, 0, 0, 0);    \
        c11 = __builtin_amdgcn_mfma_i32_32x32x32_i8(A1, B1, c11, 0, 0, 0);    \
        c20 = __builtin_amdgcn_mfma_i32_32x32x32_i8(A2, B0, c20, 0, 0, 0);    \
        c21 = __builtin_amdgcn_mfma_i32_32x32x32_i8(A2, B1, c21, 0, 0, 0);    \
        c30 = __builtin_amdgcn_mfma_i32_32x32x32_i8(A3, B0, c30, 0, 0, 0);    \
        c31 = __builtin_amdgcn_mfma_i32_32x32x32_i8(A3, B1, c31, 0, 0, 0);    \
        __builtin_amdgcn_s_setprio(0);                                        \
    }

    int16v c00 = 0, c01 = 0, c10 = 0, c11 = 0, c20 = 0, c21 = 0, c30 = 0, c31 = 0;
    int4v a0, a1, a2, a3, b0, b1;
    int4v na0, na1, na2, na3, nb0, nb1;

    // prologue: stage steps 0 and 1 (12 loads in flight)
    GSTAGE(0, 0);
    GSTAGE(1, 1);

    for (int t = 0; t < K_DIM / 64; ++t) {
        const int buf = t % 3;

        // counted wait: step-t's 6 loads landed; step-t+1's stay in flight
        if (t < K_DIM / 64 - 1)
            asm volatile("s_waitcnt vmcnt(6)" ::: "memory");
        else
            asm volatile("s_waitcnt vmcnt(0)" ::: "memory");
        __builtin_amdgcn_s_barrier();   // buf[t] ready; buf[(t+2)%3] free

        if (t + 2 < K_DIM / 64) GSTAGE((t + 2) % 3, t + 2);

        LOADP(a0, a1, a2, a3, b0, b1, buf, 0);
        LOADP(na0, na1, na2, na3, nb0, nb1, buf, 1);
        MFMA8(a0, a1, a2, a3, b0, b1);
        MFMA8(na0, na1, na2, na3, nb0, nb1);
    }
#undef MFMA8
#undef LOADP
#undef GSTAGE

    // epilogue: C/D map col=lane&31, row=(r&3)+8*(r>>2)+4*(lane>>5)
    float bv0 = bias[bcol + wcol + l31];
    float bv1 = bias[bcol + wcol + 32 + l31];
    const size_t obase = (size_t)(brow + wrow) * O_DIM + bcol + wcol;

#define CWRITE(cm, m, n, bv)                                                  \
    {                                                                         \
        _Pragma("unroll")                                                     \
        for (int r = 0; r < 16; ++r) {                                        \
            int rl = (r & 3) + 8 * (r >> 2) + 4 * lh;                         \
            out[obase + (size_t)((m) * 32 + rl) * O_DIM + (n) * 32 + l31] =   \
                (float)cm[r] + (bv);                                          \
        }                                                                     \
    }

    CWRITE(c00, 0, 0, bv0); CWRITE(c01, 0, 1, bv1);
    CWRITE(c10, 1, 0, bv0); CWRITE(c11, 1, 1, bv1);
    CWRITE(c20, 2, 0, bv0); CWRITE(c21, 2, 1, bv1);
    CWRITE(c30, 3, 0, bv0); CWRITE(c31, 3, 1, bv1);
#undef CWRITE
}

// ====================== popcount fallback (round-5, proven) =================
__global__ __launch_bounds__(256) void pack_x_kernel(
        const float* __restrict__ X, uint64_t* __restrict__ Xb) {
    int wave = (int)((blockIdx.x * blockDim.x + threadIdx.x) >> 6);
    int lane = threadIdx.x & 63;
    if (wave >= N_ROWS) return;
    const float* xr = X + (size_t)wave * K_DIM;
    uint64_t* xbr = Xb + (size_t)wave * KW;
    #pragma unroll 4
    for (int w = 0; w < KW; ++w) {
        float v = xr[w * 64 + lane];
        unsigned long long m = __ballot(v > 0.0f);
        if (lane == 0) xbr[w] = (uint64_t)m;
    }
}

__global__ __launch_bounds__(256) void pack_w_kernel(
        const float* __restrict__ W, uint64_t* __restrict__ Wb) {
    int oc = blockIdx.x & 15;
    int w  = blockIdx.x >> 4;
    int o  = oc * 256 + threadIdx.x;
    const float* wp = W + (size_t)(w * 64) * O_DIM + o;
    uint64_t word = 0;
    #pragma unroll 8
    for (int p = 0; p < 64; ++p) {
        float v = wp[(size_t)p * O_DIM];
        word |= (uint64_t)(v > 0.0f) << p;
    }
    Wb[(size_t)o * KW + w] = word;
}

__global__ __launch_bounds__(256) void xnor_gemm_kernel(
        const uint8_t* __restrict__ Xb, const uint8_t* __restrict__ Wb,
        const float* __restrict__ bias, float* __restrict__ out) {
    __shared__ uint4 lds4[2048];
    const int tid    = threadIdx.x;
    const int brow   = (blockIdx.x >> 5) * 128;
    const int bcol   = (blockIdx.x & 31) * 128;
    const int tx     = tid & 15;
    const int ty     = tid >> 4;
    const int widx   = tid >> 6;
    const int xbase0 = ty * 64 + (ty & 7);
    const int wbase0 = 1024 + tx * 64 + (tx & 7);
    uint32_t acc[8][8] = {};
    for (int kc = 0; kc < 4; ++kc) {
        __syncthreads();
        #pragma unroll
        for (int i = 0; i < 4; ++i) {
            int idx  = tid + 256 * i;
            int row  = idx >> 3;
            int srcc = (idx & 7) ^ ((idx >> 6) & 7);
            size_t goff = ((size_t)row << 9) + (kc << 7) + (srcc << 4);
            __builtin_amdgcn_global_load_lds(
                (const __attribute__((address_space(1))) void*)
                    (Xb + ((size_t)brow << 9) + goff),
                (__attribute__((address_space(3))) void*)
                    (lds4 + i * 256 + widx * 64), 16, 0, 0);
            __builtin_amdgcn_global_load_lds(
                (const __attribute__((address_space(1))) void*)
                    (Wb + ((size_t)bcol << 9) + goff),
                (__attribute__((address_space(3))) void*)
                    (lds4 + 1024 + i * 256 + widx * 64), 16, 0, 0);
        }
        asm volatile("s_waitcnt vmcnt(0)" ::: "memory");
        __syncthreads();
        for (int kq = 0; kq < 8; ++kq) {
            const uint4* xp = &lds4[xbase0 ^ kq];
            const uint4* wp = &lds4[wbase0 ^ kq];
            uint4 xq[8];
            #pragma unroll
            for (int r = 0; r < 8; ++r) xq[r] = xp[8 * r];
            #pragma unroll
            for (int c = 0; c < 8; ++c) {
                uint4 wv = wp[8 * c];
                #pragma unroll
                for (int r = 0; r < 8; ++r) {
                    uint32_t a = acc[r][c];
                    a = __builtin_popcount(xq[r].x ^ wv.x) + a;
                    a = __builtin_popcount(xq[r].y ^ wv.y) + a;
                    a = __builtin_popcount(xq[r].z ^ wv.z) + a;
                    a = __builtin_popcount(xq[r].w ^ wv.w) + a;
                    acc[r][c] = a;
                }
            }
        }
    }
    float bv[8];
    #pragma unroll
    for (int c = 0; c < 8; ++c) bv[c] = bias[bcol + tx * 8 + c];
    #pragma unroll
    for (int r = 0; r < 8; ++r) {
        float vals[8];
        #pragma unroll
        for (int c = 0; c < 8; ++c)
            vals[c] = (float)(K_DIM - 2 * (int)acc[r][c]) + bv[c];
        float4* op = (float4*)(out + (size_t)(brow + ty * 8 + r) * O_DIM
                               + bcol + tx * 8);
        op[0] = make_float4(vals[0], vals[1], vals[2], vals[3]);
        op[1] = make_float4(vals[4], vals[5], vals[6], vals[7]);
    }
}

// ====================== launcher ============================================
extern "C" void kernel_launch(void* const* d_in, const int* in_sizes, int n_in,
                              void* d_out, int out_size, void* d_ws, size_t ws_size,
                              hipStream_t stream) {
    const float* X    = (const float*)d_in[0];
    const float* W    = (const float*)d_in[1];
    const float* bias = (const float*)d_in[2];
    float* out        = (float*)d_out;

    const size_t XB_BYTES = (size_t)N_ROWS * K_DIM;   // 32 MiB blocked X
    const size_t WB_BYTES = (size_t)O_DIM * K_DIM;    // 16 MiB blocked W

    if (ws_size >= XB_BYTES + WB_BYTES) {
        int8_t* XBlk = (int8_t*)d_ws;
        int8_t* WBlk = (int8_t*)d_ws + XB_BYTES;

        convert_x_kernel<<<(N_ROWS * K_DIM / 16) / 256, 256, 0, stream>>>(X, XBlk);
        convert_w_kernel<<<(O_DIM * K_DIM / 16) / 256, 256, 0, stream>>>(W, WBlk);
        i8_gemm256_kernel<<<(N_ROWS / 256) * (O_DIM / 128), 256, 0, stream>>>(
            XBlk, WBlk, bias, out);
    } else {
        uint64_t* Xb = (uint64_t*)d_ws;
        uint64_t* Wb = (uint64_t*)((uint8_t*)d_ws + (size_t)N_ROWS * KW * 8);
        pack_x_kernel<<<N_ROWS / 4, 256, 0, stream>>>(X, Xb);
        pack_w_kernel<<<16 * 64, 256, 0, stream>>>(W, Wb);
        xnor_gemm_kernel<<<(N_ROWS / 128) * (O_DIM / 128), 256, 0, stream>>>(
            (const uint8_t*)Xb, (const uint8_t*)Wb, bias, out);
    }
}

// Round 18
// 188.956 us; speedup vs baseline: 1.0277x; 1.0277x over previous
//
#include <hip/hip_runtime.h>
#include <stdint.h>

// BinarizeLinear inference: out = sign(X) @ sign(W) + bias
// Round 18: break the ds_read->MFMA in-step dependency. BK=32 steps, 4-deep
// LDS buffers (48 KiB, 2 blocks/CU), stage 3 ahead w/ counted vmcnt(3);
// each step: barrier -> GSTAGE(t+3) -> LOADP(frags for t+1) -> MFMA8(frags
// loaded at t-1, no lgkm wait) -- LDS port runs UNDER the matrix pipe.
// Static 2-set register dbuf (rule 20). Exact integer math.

#define N_ROWS 8192
#define K_DIM  4096
#define O_DIM  4096
#define KW     64

typedef int int4v  __attribute__((ext_vector_type(4)));
typedef int int16v __attribute__((ext_vector_type(16)));

// ====================== X -> fragment-blocked i8 ([G][kt][p][g]) ============
__global__ __launch_bounds__(256) void convert_x_kernel(
        const float* __restrict__ X, int8_t* __restrict__ XBlk) {
    int u    = blockIdx.x * 4 + (threadIdx.x >> 6);   // piece id, [0, 32768)
    int lane = threadIdx.x & 63;
    int g = u & 7, p = (u >> 3) & 3, kt = (u >> 5) & 31, G = u >> 10;
    int n    = G * 256 + g * 32 + (lane & 31);
    int kcol = kt * 128 + p * 32 + (lane >> 5) * 16;
    const float4* src = (const float4*)(X + (size_t)n * K_DIM + kcol);
    uint32_t ow[4];
    #pragma unroll
    for (int q = 0; q < 4; ++q) {
        float4 v = src[q];
        uint32_t b0 = v.x > 0.0f ? 0x01u : 0xFFu;
        uint32_t b1 = v.y > 0.0f ? 0x01u : 0xFFu;
        uint32_t b2 = v.z > 0.0f ? 0x01u : 0xFFu;
        uint32_t b3 = v.w > 0.0f ? 0x01u : 0xFFu;
        ow[q] = b0 | (b1 << 8) | (b2 << 16) | (b3 << 24);
    }
    int4v o; o.x = ow[0]; o.y = ow[1]; o.z = ow[2]; o.w = ow[3];
    *(int4v*)(XBlk + (size_t)u * 1024 + lane * 16) = o;
}

// ====================== W (f32 [in][out]) -> blocked i8 ([G][kt][p][g]) =====
__global__ __launch_bounds__(256) void convert_w_kernel(
        const float* __restrict__ W, int8_t* __restrict__ WBlk) {
    int u    = blockIdx.x * 4 + (threadIdx.x >> 6);   // piece id, [0, 16384)
    int lane = threadIdx.x & 63;
    int g = u & 7, p = (u >> 3) & 3, kt = (u >> 5) & 31, G = u >> 10;
    int o     = G * 256 + g * 32 + (lane & 31);
    int kbase = kt * 128 + p * 32 + (lane >> 5) * 16;
    const float* src = W + (size_t)kbase * O_DIM + o;
    uint32_t ow[4];
    #pragma unroll
    for (int q = 0; q < 4; ++q) {
        uint32_t v = 0;
        #pragma unroll
        for (int b = 0; b < 4; ++b) {
            float f = src[(size_t)(q * 4 + b) * O_DIM];
            v |= (f > 0.0f ? 0x01u : 0xFFu) << (8 * b);
        }
        ow[q] = v;
    }
    int4v ov; ov.x = ow[0]; ov.y = ow[1]; ov.z = ow[2]; ov.w = ow[3];
    *(int4v*)(WBlk + (size_t)u * 1024 + lane * 16) = ov;
}

// ====================== 256x128 i8 GEMM, decoupled read/MFMA pipeline =======
// Grid 1024 (32M x 32N), 256 thr / 4 waves, per-wave 128x64 (4x2 of 32x32).
// BK=32 (1 cluster/step, 128 steps). LDS 4 x [A 8KB | B 4KB] = 48 KiB.
__global__ __launch_bounds__(256, 2) void i8_gemm256_kernel(
        const int8_t* __restrict__ XBlk, const int8_t* __restrict__ WBlk,
        const float* __restrict__ bias, float* __restrict__ out) {
    __shared__ int8_t lds[4 * 12288];    // 48 KiB

    const int tid  = threadIdx.x;
    const int swzb = (blockIdx.x & 7) * 128 + (blockIdx.x >> 3);  // XCD swizzle
    const int brow = (swzb >> 5) * 256;
    const int bcol = (swzb & 31) * 128;

    const int lane = tid & 63;
    const int wid  = tid >> 6;
    const int wrow = (wid >> 1) * 128;   // 2 M-groups
    const int wcol = (wid & 1) * 64;     // 2 N-groups
    const int l31  = lane & 31;
    const int lh   = lane >> 5;

    const int ag0 = (wrow >> 5) * 1024;          // 0 or 4096 (A half)
    const int bg0 = 8192 + (wcol >> 5) * 1024;   // B base + 0 or 2048

    // step t source offset = t*8192 in the [G][kt][p][g] layout
    const int8_t* Asrc = XBlk + ((size_t)(brow >> 8) << 20) + tid * 16;
    const int8_t* Bsrc = WBlk + ((size_t)(bcol >> 8) << 20)
                              + ((bcol & 255) >> 5) * 1024 + tid * 16;

#define GSTAGE(buf, t)                                                        \
    {                                                                         \
        _Pragma("unroll")                                                     \
        for (int j = 0; j < 2; ++j) {                                         \
            __builtin_amdgcn_global_load_lds(                                 \
                (const __attribute__((address_space(1))) void*)               \
                    (Asrc + (size_t)(t) * 8192 + j * 4096),                   \
                (__attribute__((address_space(3))) void*)                     \
                    (lds + (buf) * 12288 + j * 4096 + tid * 16), 16, 0, 0);   \
        }                                                                     \
        __builtin_amdgcn_global_load_lds(                                     \
            (const __attribute__((address_space(1))) void*)                   \
                (Bsrc + (size_t)(t) * 8192),                                  \
            (__attribute__((address_space(3))) void*)                         \
                (lds + (buf) * 12288 + 8192 + tid * 16), 16, 0, 0);           \
    }

#define LOADP(A0, A1, A2, A3, B0, B1, buf)                                    \
    {                                                                         \
        const int8_t* Ap = lds + (buf) * 12288 + ag0 + lane * 16;             \
        const int8_t* Bp = lds + (buf) * 12288 + bg0 + lane * 16;             \
        A0 = *(const int4v*)(Ap);                                             \
        A1 = *(const int4v*)(Ap + 1024);                                      \
        A2 = *(const int4v*)(Ap + 2048);                                      \
        A3 = *(const int4v*)(Ap + 3072);                                      \
        B0 = *(const int4v*)(Bp);                                             \
        B1 = *(const int4v*)(Bp + 1024);                                      \
    }

#define MFMA8(A0, A1, A2, A3, B0, B1)                                         \
    {                                                                         \
        __builtin_amdgcn_s_setprio(1);                                        \
        c00 = __builtin_amdgcn_mfma_i32_32x32x32_i8(A0, B0, c00, 0, 0, 0);    \
        c01 = __builtin_amdgcn_mfma_i32_32x32x32_i8(A0, B1, c01, 0, 0, 0);    \
        c10 = __builtin_amdgcn_mfma_i32_32x32x32_i8(A1, B0, c10, 0, 0, 0);    \
        c11 = __builtin_amdgcn_mfma_i32_32x32x32_i8(A1, B1, c11, 0, 0, 0);    \
        c20 = __builtin_amdgcn_mfma_i32_32x32x32_i8(A2, B0, c20, 0, 0, 0);    \
        c21 = __builtin_amdgcn_mfma_i32_32x32x32_i8(A2, B1, c21, 0, 0, 0);    \
        c30 = __builtin_amdgcn_mfma_i32_32x32x32_i8(A3, B0, c30, 0, 0, 0);    \
        c31 = __builtin_amdgcn_mfma_i32_32x32x32_i8(A3, B1, c31, 0, 0, 0);    \
        __builtin_amdgcn_s_setprio(0);                                        \
    }

    int16v c00 = 0, c01 = 0, c10 = 0, c11 = 0, c20 = 0, c21 = 0, c30 = 0, c31 = 0;
    int4v a0, a1, a2, a3, b0, b1;        // set0 (even steps)
    int4v na0, na1, na2, na3, nb0, nb1;  // set1 (odd steps)

    // prologue: stage steps 0,1,2 (9 loads/thread); wait step-0 (vmcnt 6)
    GSTAGE(0, 0);
    GSTAGE(1, 1);
    GSTAGE(2, 2);
    asm volatile("s_waitcnt vmcnt(6)" ::: "memory");
    __builtin_amdgcn_s_barrier();
    LOADP(a0, a1, a2, a3, b0, b1, 0);

    // steady state: step pairs (0,1)..(122,123). At step t: in-flight stages
    // t+1,t+2 (6 loads/thread) -> vmcnt(3) retires t+1's; barrier; stage t+3;
    // read t+1 frags; MFMA on t frags (loaded last step - no lgkm dep).
    for (int i = 0; i < 62; ++i) {
        const int t0 = 2 * i;
        // step t0 (compute set0, load set1)
        asm volatile("s_waitcnt vmcnt(3)" ::: "memory");
        __builtin_amdgcn_s_barrier();
        GSTAGE((t0 + 3) & 3, t0 + 3);
        LOADP(na0, na1, na2, na3, nb0, nb1, (t0 + 1) & 3);
        MFMA8(a0, a1, a2, a3, b0, b1);
        // step t0+1 (compute set1, load set0)
        asm volatile("s_waitcnt vmcnt(3)" ::: "memory");
        __builtin_amdgcn_s_barrier();
        GSTAGE((t0 + 4) & 3, t0 + 4);
        LOADP(a0, a1, a2, a3, b0, b1, (t0 + 2) & 3);
        MFMA8(na0, na1, na2, na3, nb0, nb1);
    }
    // t=124 (set0): stage 127, read 125
    asm volatile("s_waitcnt vmcnt(3)" ::: "memory");
    __builtin_amdgcn_s_barrier();
    GSTAGE(127 & 3, 127);
    LOADP(na0, na1, na2, na3, nb0, nb1, 125 & 3);
    MFMA8(a0, a1, a2, a3, b0, b1);
    // t=125 (set1): read 126 (in-flight 126,127 -> vmcnt(3))
    asm volatile("s_waitcnt vmcnt(3)" ::: "memory");
    __builtin_amdgcn_s_barrier();
    LOADP(a0, a1, a2, a3, b0, b1, 126 & 3);
    MFMA8(na0, na1, na2, na3, nb0, nb1);
    // t=126 (set0): read 127 (in-flight 127 only -> vmcnt(0))
    asm volatile("s_waitcnt vmcnt(0)" ::: "memory");
    __builtin_amdgcn_s_barrier();
    LOADP(na0, na1, na2, na3, nb0, nb1, 127 & 3);
    MFMA8(a0, a1, a2, a3, b0, b1);
    // t=127 (set1)
    MFMA8(na0, na1, na2, na3, nb0, nb1);
#undef MFMA8
#undef LOADP
#undef GSTAGE

    // epilogue: C/D map col=lane&31, row=(r&3)+8*(r>>2)+4*(lane>>5)
    float bv0 = bias[bcol + wcol + l31];
    float bv1 = bias[bcol + wcol + 32 + l31];
    const size_t obase = (size_t)(brow + wrow) * O_DIM + bcol + wcol;

#define CWRITE(cm, m, n, bv)                                                  \
    {                                                                         \
        _Pragma("unroll")                                                     \
        for (int r = 0; r < 16; ++r) {                                        \
            int rl = (r & 3) + 8 * (r >> 2) + 4 * lh;                         \
            out[obase + (size_t)((m) * 32 + rl) * O_DIM + (n) * 32 + l31] =   \
                (float)cm[r] + (bv);                                          \
        }                                                                     \
    }

    CWRITE(c00, 0, 0, bv0); CWRITE(c01, 0, 1, bv1);
    CWRITE(c10, 1, 0, bv0); CWRITE(c11, 1, 1, bv1);
    CWRITE(c20, 2, 0, bv0); CWRITE(c21, 2, 1, bv1);
    CWRITE(c30, 3, 0, bv0); CWRITE(c31, 3, 1, bv1);
#undef CWRITE
}

// ====================== popcount fallback (round-5, proven) =================
__global__ __launch_bounds__(256) void pack_x_kernel(
        const float* __restrict__ X, uint64_t* __restrict__ Xb) {
    int wave = (int)((blockIdx.x * blockDim.x + threadIdx.x) >> 6);
    int lane = threadIdx.x & 63;
    if (wave >= N_ROWS) return;
    const float* xr = X + (size_t)wave * K_DIM;
    uint64_t* xbr = Xb + (size_t)wave * KW;
    #pragma unroll 4
    for (int w = 0; w < KW; ++w) {
        float v = xr[w * 64 + lane];
        unsigned long long m = __ballot(v > 0.0f);
        if (lane == 0) xbr[w] = (uint64_t)m;
    }
}

__global__ __launch_bounds__(256) void pack_w_kernel(
        const float* __restrict__ W, uint64_t* __restrict__ Wb) {
    int oc = blockIdx.x & 15;
    int w  = blockIdx.x >> 4;
    int o  = oc * 256 + threadIdx.x;
    const float* wp = W + (size_t)(w * 64) * O_DIM + o;
    uint64_t word = 0;
    #pragma unroll 8
    for (int p = 0; p < 64; ++p) {
        float v = wp[(size_t)p * O_DIM];
        word |= (uint64_t)(v > 0.0f) << p;
    }
    Wb[(size_t)o * KW + w] = word;
}

__global__ __launch_bounds__(256) void xnor_gemm_kernel(
        const uint8_t* __restrict__ Xb, const uint8_t* __restrict__ Wb,
        const float* __restrict__ bias, float* __restrict__ out) {
    __shared__ uint4 lds4[2048];
    const int tid    = threadIdx.x;
    const int brow   = (blockIdx.x >> 5) * 128;
    const int bcol   = (blockIdx.x & 31) * 128;
    const int tx     = tid & 15;
    const int ty     = tid >> 4;
    const int widx   = tid >> 6;
    const int xbase0 = ty * 64 + (ty & 7);
    const int wbase0 = 1024 + tx * 64 + (tx & 7);
    uint32_t acc[8][8] = {};
    for (int kc = 0; kc < 4; ++kc) {
        __syncthreads();
        #pragma unroll
        for (int i = 0; i < 4; ++i) {
            int idx  = tid + 256 * i;
            int row  = idx >> 3;
            int srcc = (idx & 7) ^ ((idx >> 6) & 7);
            size_t goff = ((size_t)row << 9) + (kc << 7) + (srcc << 4);
            __builtin_amdgcn_global_load_lds(
                (const __attribute__((address_space(1))) void*)
                    (Xb + ((size_t)brow << 9) + goff),
                (__attribute__((address_space(3))) void*)
                    (lds4 + i * 256 + widx * 64), 16, 0, 0);
            __builtin_amdgcn_global_load_lds(
                (const __attribute__((address_space(1))) void*)
                    (Wb + ((size_t)bcol << 9) + goff),
                (__attribute__((address_space(3))) void*)
                    (lds4 + 1024 + i * 256 + widx * 64), 16, 0, 0);
        }
        asm volatile("s_waitcnt vmcnt(0)" ::: "memory");
        __syncthreads();
        for (int kq = 0; kq < 8; ++kq) {
            const uint4* xp = &lds4[xbase0 ^ kq];
            const uint4* wp = &lds4[wbase0 ^ kq];
            uint4 xq[8];
            #pragma unroll
            for (int r = 0; r < 8; ++r) xq[r] = xp[8 * r];
            #pragma unroll
            for (int c = 0; c < 8; ++c) {
                uint4 wv = wp[8 * c];
                #pragma unroll
                for (int r = 0; r < 8; ++r) {
                    uint32_t a = acc[r][c];
                    a = __builtin_popcount(xq[r].x ^ wv.x) + a;
                    a = __builtin_popcount(xq[r].y ^ wv.y) + a;
                    a = __builtin_popcount(xq[r].z ^ wv.z) + a;
                    a = __builtin_popcount(xq[r].w ^ wv.w) + a;
                    acc[r][c] = a;
                }
            }
        }
    }
    float bv[8];
    #pragma unroll
    for (int c = 0; c < 8; ++c) bv[c] = bias[bcol + tx * 8 + c];
    #pragma unroll
    for (int r = 0; r < 8; ++r) {
        float vals[8];
        #pragma unroll
        for (int c = 0; c < 8; ++c)
            vals[c] = (float)(K_DIM - 2 * (int)acc[r][c]) + bv[c];
        float4* op = (float4*)(out + (size_t)(brow + ty * 8 + r) * O_DIM
                               + bcol + tx * 8);
        op[0] = make_float4(vals[0], vals[1], vals[2], vals[3]);
        op[1] = make_float4(vals[4], vals[5], vals[6], vals[7]);
    }
}

// ====================== launcher ============================================
extern "C" void kernel_launch(void* const* d_in, const int* in_sizes, int n_in,
                              void* d_out, int out_size, void* d_ws, size_t ws_size,
                              hipStream_t stream) {
    const float* X    = (const float*)d_in[0];
    const float* W    = (const float*)d_in[1];
    const float* bias = (const float*)d_in[2];
    float* out        = (float*)d_out;

    const size_t XB_BYTES = (size_t)N_ROWS * K_DIM;   // 32 MiB blocked X
    const size_t WB_BYTES = (size_t)O_DIM * K_DIM;    // 16 MiB blocked W

    if (ws_size >= XB_BYTES + WB_BYTES) {
        int8_t* XBlk = (int8_t*)d_ws;
        int8_t* WBlk = (int8_t*)d_ws + XB_BYTES;

        convert_x_kernel<<<(N_ROWS * K_DIM / 16) / 256, 256, 0, stream>>>(X, XBlk);
        convert_w_kernel<<<(O_DIM * K_DIM / 16) / 256, 256, 0, stream>>>(W, WBlk);
        i8_gemm256_kernel<<<(N_ROWS / 256) * (O_DIM / 128), 256, 0, stream>>>(
            XBlk, WBlk, bias, out);
    } else {
        uint64_t* Xb = (uint64_t*)d_ws;
        uint64_t* Wb = (uint64_t*)((uint8_t*)d_ws + (size_t)N_ROWS * KW * 8);
        pack_x_kernel<<<N_ROWS / 4, 256, 0, stream>>>(X, Xb);
        pack_w_kernel<<<16 * 64, 256, 0, stream>>>(W, Wb);
        xnor_gemm_kernel<<<(N_ROWS / 128) * (O_DIM / 128), 256, 0, stream>>>(
            (const uint8_t*)Xb, (const uint8_t*)Wb, bias, out);
    }
}

// Round 19
// 129.770 us; speedup vs baseline: 1.4965x; 1.4561x over previous
//
#include <hip/hip_runtime.h>
#include <stdint.h>

// BinarizeLinear inference: out = sign(X) @ sign(W) + bias
// Round 19: MX-FP4 MFMA path. +-1 encoded as e2m1 (0x2/0xA), scales = 1.0
// (e8m0 0x7F); mfma_scale_f32_32x32x64_f8f6f4 runs at ~2x the i8 rate and
// halves LDS bytes/MAC -- attacks both terms of the measured port+matrix
// serialization (61+62 us) at once. f32 accumulate of +-1 products is exact.
// GEMM structure = round-17-proven 3-deep counted-vmcnt pipeline.

#define N_ROWS 8192
#define K_DIM  4096
#define O_DIM  4096
#define KW     64

typedef int   int4v   __attribute__((ext_vector_type(4)));
typedef int   int8v   __attribute__((ext_vector_type(8)));
typedef float float16v __attribute__((ext_vector_type(16)));

__device__ __forceinline__ int8v mk8(int4v x) {
    int8v r;
    r[0] = x[0]; r[1] = x[1]; r[2] = x[2]; r[3] = x[3];
    r[4] = 0;    r[5] = 0;    r[6] = 0;    r[7] = 0;
    return r;
}

// fp4 e2m1: +1.0 = 0x2, -1.0 = 0xA
__device__ __forceinline__ uint32_t nib4(float f) { return f > 0.0f ? 0x2u : 0xAu; }

// ====================== X -> fp4 blocked [G][kt][g][lane][16B] ==============
// piece u: G = u>>9, kt = (u>>3)&63, g = u&7. Lane l: row = G*256+g*32+(l&31),
// k = kt*64 + (l>>5)*32 .. +32 (32 elems -> 16 B, k-ascending nibbles).
__global__ __launch_bounds__(256) void convert_x_fp4(
        const float* __restrict__ X, uint8_t* __restrict__ XB) {
    int u    = blockIdx.x * 4 + (threadIdx.x >> 6);   // [0, 16384)
    int lane = threadIdx.x & 63;
    int g = u & 7, kt = (u >> 3) & 63, G = u >> 9;
    int row = G * 256 + g * 32 + (lane & 31);
    int k0  = kt * 64 + (lane >> 5) * 32;
    const float4* src = (const float4*)(X + (size_t)row * K_DIM + k0);
    uint32_t ow[4];
    #pragma unroll
    for (int q = 0; q < 4; ++q) {
        float4 vA = src[2 * q];
        float4 vB = src[2 * q + 1];
        uint32_t b0 = nib4(vA.x) | (nib4(vA.y) << 4);
        uint32_t b1 = nib4(vA.z) | (nib4(vA.w) << 4);
        uint32_t b2 = nib4(vB.x) | (nib4(vB.y) << 4);
        uint32_t b3 = nib4(vB.z) | (nib4(vB.w) << 4);
        ow[q] = b0 | (b1 << 8) | (b2 << 16) | (b3 << 24);
    }
    int4v o; o.x = (int)ow[0]; o.y = (int)ow[1]; o.z = (int)ow[2]; o.w = (int)ow[3];
    *(int4v*)(XB + (size_t)u * 1024 + lane * 16) = o;
}

// ====================== W (f32 [in][out]) -> fp4 blocked ====================
// Same piece scheme over o. Lane l: o = G*256+g*32+(l&31), k = kt*64+(l>>5)*32+j.
// Reads coalesced per k-row (lanes 0-31 adjacent o).
__global__ __launch_bounds__(256) void convert_w_fp4(
        const float* __restrict__ W, uint8_t* __restrict__ WB) {
    int u    = blockIdx.x * 4 + (threadIdx.x >> 6);   // [0, 8192)
    int lane = threadIdx.x & 63;
    int g = u & 7, kt = (u >> 3) & 63, G = u >> 9;
    int o     = G * 256 + g * 32 + (lane & 31);
    int kbase = kt * 64 + (lane >> 5) * 32;
    const float* src = W + (size_t)kbase * O_DIM + o;
    uint32_t ow[4];
    #pragma unroll
    for (int q = 0; q < 4; ++q) {
        uint32_t v = 0;
        #pragma unroll
        for (int j = 0; j < 8; ++j) {
            float f = src[(size_t)(q * 8 + j) * O_DIM];
            v |= nib4(f) << (4 * j);
        }
        ow[q] = v;
    }
    int4v ov; ov.x = (int)ow[0]; ov.y = (int)ow[1]; ov.z = (int)ow[2]; ov.w = (int)ow[3];
    *(int4v*)(WB + (size_t)u * 1024 + lane * 16) = ov;
}

// ====================== 256x128 fp4 GEMM, 3-deep counted pipeline ===========
// Grid 1024 (32M x 32N), 256 thr / 4 waves, per-wave 128x64 (4x2 of 32x32).
// Step = k=64 (64 steps). LDS 3 x [A 8KB | B 4KB] = 36 KiB.
#define MFMA4(a, b, c)                                                        \
    __builtin_amdgcn_mfma_scale_f32_32x32x64_f8f6f4(                          \
        (a), (b), (c), 4, 4, 0, 0x7F7F7F7F, 0, 0x7F7F7F7F)

__global__ __launch_bounds__(256, 2) void fp4_gemm_kernel(
        const uint8_t* __restrict__ XB, const uint8_t* __restrict__ WB,
        const float* __restrict__ bias, float* __restrict__ out) {
    __shared__ uint8_t lds[3 * 12288];   // 36 KiB

    const int tid  = threadIdx.x;
    const int swzb = (blockIdx.x & 7) * 128 + (blockIdx.x >> 3);  // XCD swizzle
    const int brow = (swzb >> 5) * 256;
    const int bcol = (swzb & 31) * 128;

    const int lane = tid & 63;
    const int wid  = tid >> 6;
    const int wrow = (wid >> 1) * 128;   // 2 M-groups
    const int wcol = (wid & 1) * 64;     // 2 N-groups
    const int l31  = lane & 31;
    const int lh   = lane >> 5;

    const int abase = (wrow >> 5) * 1024 + lane * 16;          // A region
    const int bbase = 8192 + (wcol >> 5) * 1024 + lane * 16;   // B region

    // [G][kt][g] layout: per-G bytes = 64 steps * 8192 = 1<<19
    const uint8_t* Asrc = XB + ((size_t)(brow >> 8) << 19) + tid * 16;
    const uint8_t* Bsrc = WB + ((size_t)(bcol >> 8) << 19)
                             + ((bcol & 255) >> 5) * 1024 + tid * 16;

#define GSTAGE(buf, t)                                                        \
    {                                                                         \
        _Pragma("unroll")                                                     \
        for (int j = 0; j < 2; ++j) {                                         \
            __builtin_amdgcn_global_load_lds(                                 \
                (const __attribute__((address_space(1))) void*)               \
                    (Asrc + (size_t)(t) * 8192 + j * 4096),                   \
                (__attribute__((address_space(3))) void*)                     \
                    (lds + (buf) * 12288 + j * 4096 + tid * 16), 16, 0, 0);   \
        }                                                                     \
        __builtin_amdgcn_global_load_lds(                                     \
            (const __attribute__((address_space(1))) void*)                   \
                (Bsrc + (size_t)(t) * 8192),                                  \
            (__attribute__((address_space(3))) void*)                         \
                (lds + (buf) * 12288 + 8192 + tid * 16), 16, 0, 0);           \
    }

#define LOADP(buf)                                                            \
    {                                                                         \
        const uint8_t* Ap = lds + (buf) * 12288 + abase;                      \
        const uint8_t* Bp = lds + (buf) * 12288 + bbase;                      \
        a0 = mk8(*(const int4v*)(Ap));                                        \
        a1 = mk8(*(const int4v*)(Ap + 1024));                                 \
        a2 = mk8(*(const int4v*)(Ap + 2048));                                 \
        a3 = mk8(*(const int4v*)(Ap + 3072));                                 \
        b0 = mk8(*(const int4v*)(Bp));                                        \
        b1 = mk8(*(const int4v*)(Bp + 1024));                                 \
    }

#define MFMA8()                                                               \
    {                                                                         \
        __builtin_amdgcn_s_setprio(1);                                        \
        c00 = MFMA4(a0, b0, c00);  c01 = MFMA4(a0, b1, c01);                  \
        c10 = MFMA4(a1, b0, c10);  c11 = MFMA4(a1, b1, c11);                  \
        c20 = MFMA4(a2, b0, c20);  c21 = MFMA4(a2, b1, c21);                  \
        c30 = MFMA4(a3, b0, c30);  c31 = MFMA4(a3, b1, c31);                  \
        __builtin_amdgcn_s_setprio(0);                                        \
    }

    float16v c00 = 0, c01 = 0, c10 = 0, c11 = 0,
             c20 = 0, c21 = 0, c30 = 0, c31 = 0;
    int8v a0, a1, a2, a3, b0, b1;

    // prologue: stage steps 0,1 (6 loads in flight)
    GSTAGE(0, 0);
    GSTAGE(1, 1);

    for (int t = 0; t < 64; ++t) {
        // counted wait: step-t's 3 loads landed; step-t+1's stay in flight
        if (t < 63)
            asm volatile("s_waitcnt vmcnt(3)" ::: "memory");
        else
            asm volatile("s_waitcnt vmcnt(0)" ::: "memory");
        __builtin_amdgcn_s_barrier();   // buf[t%3] ready; buf[(t+2)%3] free

        if (t + 2 < 64) GSTAGE((t + 2) % 3, t + 2);

        LOADP(t % 3);
        MFMA8();
    }
#undef MFMA8
#undef LOADP
#undef GSTAGE

    // epilogue: C/D map col=lane&31, row=(r&3)+8*(r>>2)+4*(lane>>5)
    float bv0 = bias[bcol + wcol + l31];
    float bv1 = bias[bcol + wcol + 32 + l31];
    const size_t obase = (size_t)(brow + wrow) * O_DIM + bcol + wcol;

#define CWRITE(cm, m, n, bv)                                                  \
    {                                                                         \
        _Pragma("unroll")                                                     \
        for (int r = 0; r < 16; ++r) {                                        \
            int rl = (r & 3) + 8 * (r >> 2) + 4 * lh;                         \
            out[obase + (size_t)((m) * 32 + rl) * O_DIM + (n) * 32 + l31] =   \
                cm[r] + (bv);                                                 \
        }                                                                     \
    }

    CWRITE(c00, 0, 0, bv0); CWRITE(c01, 0, 1, bv1);
    CWRITE(c10, 1, 0, bv0); CWRITE(c11, 1, 1, bv1);
    CWRITE(c20, 2, 0, bv0); CWRITE(c21, 2, 1, bv1);
    CWRITE(c30, 3, 0, bv0); CWRITE(c31, 3, 1, bv1);
#undef CWRITE
}

// ====================== popcount fallback (round-5, proven) =================
__global__ __launch_bounds__(256) void pack_x_kernel(
        const float* __restrict__ X, uint64_t* __restrict__ Xb) {
    int wave = (int)((blockIdx.x * blockDim.x + threadIdx.x) >> 6);
    int lane = threadIdx.x & 63;
    if (wave >= N_ROWS) return;
    const float* xr = X + (size_t)wave * K_DIM;
    uint64_t* xbr = Xb + (size_t)wave * KW;
    #pragma unroll 4
    for (int w = 0; w < KW; ++w) {
        float v = xr[w * 64 + lane];
        unsigned long long m = __ballot(v > 0.0f);
        if (lane == 0) xbr[w] = (uint64_t)m;
    }
}

__global__ __launch_bounds__(256) void pack_w_kernel(
        const float* __restrict__ W, uint64_t* __restrict__ Wb) {
    int oc = blockIdx.x & 15;
    int w  = blockIdx.x >> 4;
    int o  = oc * 256 + threadIdx.x;
    const float* wp = W + (size_t)(w * 64) * O_DIM + o;
    uint64_t word = 0;
    #pragma unroll 8
    for (int p = 0; p < 64; ++p) {
        float v = wp[(size_t)p * O_DIM];
        word |= (uint64_t)(v > 0.0f) << p;
    }
    Wb[(size_t)o * KW + w] = word;
}

__global__ __launch_bounds__(256) void xnor_gemm_kernel(
        const uint8_t* __restrict__ Xb, const uint8_t* __restrict__ Wb,
        const float* __restrict__ bias, float* __restrict__ out) {
    __shared__ uint4 lds4[2048];
    const int tid    = threadIdx.x;
    const int brow   = (blockIdx.x >> 5) * 128;
    const int bcol   = (blockIdx.x & 31) * 128;
    const int tx     = tid & 15;
    const int ty     = tid >> 4;
    const int widx   = tid >> 6;
    const int xbase0 = ty * 64 + (ty & 7);
    const int wbase0 = 1024 + tx * 64 + (tx & 7);
    uint32_t acc[8][8] = {};
    for (int kc = 0; kc < 4; ++kc) {
        __syncthreads();
        #pragma unroll
        for (int i = 0; i < 4; ++i) {
            int idx  = tid + 256 * i;
            int row  = idx >> 3;
            int srcc = (idx & 7) ^ ((idx >> 6) & 7);
            size_t goff = ((size_t)row << 9) + (kc << 7) + (srcc << 4);
            __builtin_amdgcn_global_load_lds(
                (const __attribute__((address_space(1))) void*)
                    (Xb + ((size_t)brow << 9) + goff),
                (__attribute__((address_space(3))) void*)
                    (lds4 + i * 256 + widx * 64), 16, 0, 0);
            __builtin_amdgcn_global_load_lds(
                (const __attribute__((address_space(1))) void*)
                    (Wb + ((size_t)bcol << 9) + goff),
                (__attribute__((address_space(3))) void*)
                    (lds4 + 1024 + i * 256 + widx * 64), 16, 0, 0);
        }
        asm volatile("s_waitcnt vmcnt(0)" ::: "memory");
        __syncthreads();
        for (int kq = 0; kq < 8; ++kq) {
            const uint4* xp = &lds4[xbase0 ^ kq];
            const uint4* wp = &lds4[wbase0 ^ kq];
            uint4 xq[8];
            #pragma unroll
            for (int r = 0; r < 8; ++r) xq[r] = xp[8 * r];
            #pragma unroll
            for (int c = 0; c < 8; ++c) {
                uint4 wv = wp[8 * c];
                #pragma unroll
                for (int r = 0; r < 8; ++r) {
                    uint32_t a = acc[r][c];
                    a = __builtin_popcount(xq[r].x ^ wv.x) + a;
                    a = __builtin_popcount(xq[r].y ^ wv.y) + a;
                    a = __builtin_popcount(xq[r].z ^ wv.z) + a;
                    a = __builtin_popcount(xq[r].w ^ wv.w) + a;
                    acc[r][c] = a;
                }
            }
        }
    }
    float bv[8];
    #pragma unroll
    for (int c = 0; c < 8; ++c) bv[c] = bias[bcol + tx * 8 + c];
    #pragma unroll
    for (int r = 0; r < 8; ++r) {
        float vals[8];
        #pragma unroll
        for (int c = 0; c < 8; ++c)
            vals[c] = (float)(K_DIM - 2 * (int)acc[r][c]) + bv[c];
        float4* op = (float4*)(out + (size_t)(brow + ty * 8 + r) * O_DIM
                               + bcol + tx * 8);
        op[0] = make_float4(vals[0], vals[1], vals[2], vals[3]);
        op[1] = make_float4(vals[4], vals[5], vals[6], vals[7]);
    }
}

// ====================== launcher ============================================
extern "C" void kernel_launch(void* const* d_in, const int* in_sizes, int n_in,
                              void* d_out, int out_size, void* d_ws, size_t ws_size,
                              hipStream_t stream) {
    const float* X    = (const float*)d_in[0];
    const float* W    = (const float*)d_in[1];
    const float* bias = (const float*)d_in[2];
    float* out        = (float*)d_out;

    const size_t XB4 = (size_t)N_ROWS * K_DIM / 2;   // 16 MiB fp4 X
    const size_t WB4 = (size_t)O_DIM * K_DIM / 2;    //  8 MiB fp4 W

    if (ws_size >= XB4 + WB4) {
        uint8_t* XBlk = (uint8_t*)d_ws;
        uint8_t* WBlk = (uint8_t*)d_ws + XB4;

        convert_x_fp4<<<16384 / 4, 256, 0, stream>>>(X, XBlk);
        convert_w_fp4<<<8192 / 4, 256, 0, stream>>>(W, WBlk);
        fp4_gemm_kernel<<<(N_ROWS / 256) * (O_DIM / 128), 256, 0, stream>>>(
            XBlk, WBlk, bias, out);
    } else {
        uint64_t* Xb = (uint64_t*)d_ws;
        uint64_t* Wb = (uint64_t*)((uint8_t*)d_ws + (size_t)N_ROWS * KW * 8);
        pack_x_kernel<<<N_ROWS / 4, 256, 0, stream>>>(X, Xb);
        pack_w_kernel<<<16 * 64, 256, 0, stream>>>(W, Wb);
        xnor_gemm_kernel<<<(N_ROWS / 128) * (O_DIM / 128), 256, 0, stream>>>(
            (const uint8_t*)Xb, (const uint8_t*)Wb, bias, out);
    }
}

// Round 20
// 128.613 us; speedup vs baseline: 1.5099x; 1.0090x over previous
//
#include <hip/hip_runtime.h>
#include <stdint.h>

// BinarizeLinear inference: out = sign(X) @ sign(W) + bias
// Round 20: fp4 GEMM VALU cleanup. (1) operand high-half = undef via
// shufflevector (fp4 FMT reads only low 4 regs) -- removes 24 v_mov/step;
// (2) step loop unrolled 3x so buffer indices are compile-time (no modulo).
// Structure otherwise = round-19 (3-deep counted-vmcnt, 256x128, 4 waves).

#define N_ROWS 8192
#define K_DIM  4096
#define O_DIM  4096
#define KW     64

typedef int   int4v    __attribute__((ext_vector_type(4)));
typedef int   int8v    __attribute__((ext_vector_type(8)));
typedef float float16v __attribute__((ext_vector_type(16)));

// fp4 operand: low 4 regs carry data, high 4 undef (FMT=fp4 ignores them)
__device__ __forceinline__ int8v mk8u(int4v x) {
    return __builtin_shufflevector(x, x, 0, 1, 2, 3, -1, -1, -1, -1);
}

// fp4 e2m1: +1.0 = 0x2, -1.0 = 0xA
__device__ __forceinline__ uint32_t nib4(float f) { return f > 0.0f ? 0x2u : 0xAu; }

// ====================== X -> fp4 blocked [G][kt][g][lane][16B] ==============
__global__ __launch_bounds__(256) void convert_x_fp4(
        const float* __restrict__ X, uint8_t* __restrict__ XB) {
    int u    = blockIdx.x * 4 + (threadIdx.x >> 6);   // [0, 16384)
    int lane = threadIdx.x & 63;
    int g = u & 7, kt = (u >> 3) & 63, G = u >> 9;
    int row = G * 256 + g * 32 + (lane & 31);
    int k0  = kt * 64 + (lane >> 5) * 32;
    const float4* src = (const float4*)(X + (size_t)row * K_DIM + k0);
    uint32_t ow[4];
    #pragma unroll
    for (int q = 0; q < 4; ++q) {
        float4 vA = src[2 * q];
        float4 vB = src[2 * q + 1];
        uint32_t b0 = nib4(vA.x) | (nib4(vA.y) << 4);
        uint32_t b1 = nib4(vA.z) | (nib4(vA.w) << 4);
        uint32_t b2 = nib4(vB.x) | (nib4(vB.y) << 4);
        uint32_t b3 = nib4(vB.z) | (nib4(vB.w) << 4);
        ow[q] = b0 | (b1 << 8) | (b2 << 16) | (b3 << 24);
    }
    int4v o; o.x = (int)ow[0]; o.y = (int)ow[1]; o.z = (int)ow[2]; o.w = (int)ow[3];
    *(int4v*)(XB + (size_t)u * 1024 + lane * 16) = o;
}

// ====================== W (f32 [in][out]) -> fp4 blocked ====================
__global__ __launch_bounds__(256) void convert_w_fp4(
        const float* __restrict__ W, uint8_t* __restrict__ WB) {
    int u    = blockIdx.x * 4 + (threadIdx.x >> 6);   // [0, 8192)
    int lane = threadIdx.x & 63;
    int g = u & 7, kt = (u >> 3) & 63, G = u >> 9;
    int o     = G * 256 + g * 32 + (lane & 31);
    int kbase = kt * 64 + (lane >> 5) * 32;
    const float* src = W + (size_t)kbase * O_DIM + o;
    uint32_t ow[4];
    #pragma unroll
    for (int q = 0; q < 4; ++q) {
        uint32_t v = 0;
        #pragma unroll
        for (int j = 0; j < 8; ++j) {
            float f = src[(size_t)(q * 8 + j) * O_DIM];
            v |= nib4(f) << (4 * j);
        }
        ow[q] = v;
    }
    int4v ov; ov.x = (int)ow[0]; ov.y = (int)ow[1]; ov.z = (int)ow[2]; ov.w = (int)ow[3];
    *(int4v*)(WB + (size_t)u * 1024 + lane * 16) = ov;
}

// ====================== 256x128 fp4 GEMM, 3-deep counted pipeline ===========
#define MFMA4(a, b, c)                                                        \
    __builtin_amdgcn_mfma_scale_f32_32x32x64_f8f6f4(                          \
        (a), (b), (c), 4, 4, 0, 0x7F7F7F7F, 0, 0x7F7F7F7F)

__global__ __launch_bounds__(256, 2) void fp4_gemm_kernel(
        const uint8_t* __restrict__ XB, const uint8_t* __restrict__ WB,
        const float* __restrict__ bias, float* __restrict__ out) {
    __shared__ uint8_t lds[3 * 12288];   // 36 KiB

    const int tid  = threadIdx.x;
    const int swzb = (blockIdx.x & 7) * 128 + (blockIdx.x >> 3);  // XCD swizzle
    const int brow = (swzb >> 5) * 256;
    const int bcol = (swzb & 31) * 128;

    const int lane = tid & 63;
    const int wid  = tid >> 6;
    const int wrow = (wid >> 1) * 128;   // 2 M-groups
    const int wcol = (wid & 1) * 64;     // 2 N-groups
    const int l31  = lane & 31;
    const int lh   = lane >> 5;

    const int abase = (wrow >> 5) * 1024 + lane * 16;          // A region
    const int bbase = 8192 + (wcol >> 5) * 1024 + lane * 16;   // B region

    const uint8_t* Asrc = XB + ((size_t)(brow >> 8) << 19) + tid * 16;
    const uint8_t* Bsrc = WB + ((size_t)(bcol >> 8) << 19)
                             + ((bcol & 255) >> 5) * 1024 + tid * 16;

#define GSTAGE(buf, t)                                                        \
    {                                                                         \
        _Pragma("unroll")                                                     \
        for (int j = 0; j < 2; ++j) {                                         \
            __builtin_amdgcn_global_load_lds(                                 \
                (const __attribute__((address_space(1))) void*)               \
                    (Asrc + (size_t)(t) * 8192 + j * 4096),                   \
                (__attribute__((address_space(3))) void*)                     \
                    (lds + (buf) * 12288 + j * 4096 + tid * 16), 16, 0, 0);   \
        }                                                                     \
        __builtin_amdgcn_global_load_lds(                                     \
            (const __attribute__((address_space(1))) void*)                   \
                (Bsrc + (size_t)(t) * 8192),                                  \
            (__attribute__((address_space(3))) void*)                         \
                (lds + (buf) * 12288 + 8192 + tid * 16), 16, 0, 0);           \
    }

#define LOADP(buf)                                                            \
    {                                                                         \
        const uint8_t* Ap = lds + (buf) * 12288 + abase;                      \
        const uint8_t* Bp = lds + (buf) * 12288 + bbase;                      \
        a0 = mk8u(*(const int4v*)(Ap));                                       \
        a1 = mk8u(*(const int4v*)(Ap + 1024));                                \
        a2 = mk8u(*(const int4v*)(Ap + 2048));                                \
        a3 = mk8u(*(const int4v*)(Ap + 3072));                                \
        b0 = mk8u(*(const int4v*)(Bp));                                       \
        b1 = mk8u(*(const int4v*)(Bp + 1024));                                \
    }

#define MFMA8()                                                               \
    {                                                                         \
        __builtin_amdgcn_s_setprio(1);                                        \
        c00 = MFMA4(a0, b0, c00);  c01 = MFMA4(a0, b1, c01);                  \
        c10 = MFMA4(a1, b0, c10);  c11 = MFMA4(a1, b1, c11);                  \
        c20 = MFMA4(a2, b0, c20);  c21 = MFMA4(a2, b1, c21);                  \
        c30 = MFMA4(a3, b0, c30);  c31 = MFMA4(a3, b1, c31);                  \
        __builtin_amdgcn_s_setprio(0);                                        \
    }

    // one pipeline step: wait -> barrier -> stage(t+2) -> read -> mfma
#define STEP(bufc, bufs, t, LASTWAIT)                                         \
    {                                                                         \
        if (LASTWAIT) asm volatile("s_waitcnt vmcnt(0)" ::: "memory");        \
        else          asm volatile("s_waitcnt vmcnt(3)" ::: "memory");        \
        __builtin_amdgcn_s_barrier();                                         \
        if ((t) + 2 < 64) GSTAGE(bufs, (t) + 2);                              \
        LOADP(bufc);                                                          \
        MFMA8();                                                              \
    }

    float16v c00 = 0, c01 = 0, c10 = 0, c11 = 0,
             c20 = 0, c21 = 0, c30 = 0, c31 = 0;
    int8v a0, a1, a2, a3, b0, b1;

    // prologue: stage steps 0,1 (6 loads in flight)
    GSTAGE(0, 0);
    GSTAGE(1, 1);

    // t = 0..62 in 21 statically-indexed triples; tail t = 63 (buf 0)
    for (int i = 0; i < 21; ++i) {
        const int t = 3 * i;
        STEP(0, 2, t,     false);
        STEP(1, 0, t + 1, false);
        STEP(2, 1, t + 2, false);
    }
    STEP(0, 2, 63, true);
#undef STEP
#undef MFMA8
#undef LOADP
#undef GSTAGE

    // epilogue: C/D map col=lane&31, row=(r&3)+8*(r>>2)+4*(lane>>5)
    float bv0 = bias[bcol + wcol + l31];
    float bv1 = bias[bcol + wcol + 32 + l31];
    const size_t obase = (size_t)(brow + wrow) * O_DIM + bcol + wcol;

#define CWRITE(cm, m, n, bv)                                                  \
    {                                                                         \
        _Pragma("unroll")                                                     \
        for (int r = 0; r < 16; ++r) {                                        \
            int rl = (r & 3) + 8 * (r >> 2) + 4 * lh;                         \
            out[obase + (size_t)((m) * 32 + rl) * O_DIM + (n) * 32 + l31] =   \
                cm[r] + (bv);                                                 \
        }                                                                     \
    }

    CWRITE(c00, 0, 0, bv0); CWRITE(c01, 0, 1, bv1);
    CWRITE(c10, 1, 0, bv0); CWRITE(c11, 1, 1, bv1);
    CWRITE(c20, 2, 0, bv0); CWRITE(c21, 2, 1, bv1);
    CWRITE(c30, 3, 0, bv0); CWRITE(c31, 3, 1, bv1);
#undef CWRITE
}

// ====================== popcount fallback (round-5, proven) =================
__global__ __launch_bounds__(256) void pack_x_kernel(
        const float* __restrict__ X, uint64_t* __restrict__ Xb) {
    int wave = (int)((blockIdx.x * blockDim.x + threadIdx.x) >> 6);
    int lane = threadIdx.x & 63;
    if (wave >= N_ROWS) return;
    const float* xr = X + (size_t)wave * K_DIM;
    uint64_t* xbr = Xb + (size_t)wave * KW;
    #pragma unroll 4
    for (int w = 0; w < KW; ++w) {
        float v = xr[w * 64 + lane];
        unsigned long long m = __ballot(v > 0.0f);
        if (lane == 0) xbr[w] = (uint64_t)m;
    }
}

__global__ __launch_bounds__(256) void pack_w_kernel(
        const float* __restrict__ W, uint64_t* __restrict__ Wb) {
    int oc = blockIdx.x & 15;
    int w  = blockIdx.x >> 4;
    int o  = oc * 256 + threadIdx.x;
    const float* wp = W + (size_t)(w * 64) * O_DIM + o;
    uint64_t word = 0;
    #pragma unroll 8
    for (int p = 0; p < 64; ++p) {
        float v = wp[(size_t)p * O_DIM];
        word |= (uint64_t)(v > 0.0f) << p;
    }
    Wb[(size_t)o * KW + w] = word;
}

__global__ __launch_bounds__(256) void xnor_gemm_kernel(
        const uint8_t* __restrict__ Xb, const uint8_t* __restrict__ Wb,
        const float* __restrict__ bias, float* __restrict__ out) {
    __shared__ uint4 lds4[2048];
    const int tid    = threadIdx.x;
    const int brow   = (blockIdx.x >> 5) * 128;
    const int bcol   = (blockIdx.x & 31) * 128;
    const int tx     = tid & 15;
    const int ty     = tid >> 4;
    const int widx   = tid >> 6;
    const int xbase0 = ty * 64 + (ty & 7);
    const int wbase0 = 1024 + tx * 64 + (tx & 7);
    uint32_t acc[8][8] = {};
    for (int kc = 0; kc < 4; ++kc) {
        __syncthreads();
        #pragma unroll
        for (int i = 0; i < 4; ++i) {
            int idx  = tid + 256 * i;
            int row  = idx >> 3;
            int srcc = (idx & 7) ^ ((idx >> 6) & 7);
            size_t goff = ((size_t)row << 9) + (kc << 7) + (srcc << 4);
            __builtin_amdgcn_global_load_lds(
                (const __attribute__((address_space(1))) void*)
                    (Xb + ((size_t)brow << 9) + goff),
                (__attribute__((address_space(3))) void*)
                    (lds4 + i * 256 + widx * 64), 16, 0, 0);
            __builtin_amdgcn_global_load_lds(
                (const __attribute__((address_space(1))) void*)
                    (Wb + ((size_t)bcol << 9) + goff),
                (__attribute__((address_space(3))) void*)
                    (lds4 + 1024 + i * 256 + widx * 64), 16, 0, 0);
        }
        asm volatile("s_waitcnt vmcnt(0)" ::: "memory");
        __syncthreads();
        for (int kq = 0; kq < 8; ++kq) {
            const uint4* xp = &lds4[xbase0 ^ kq];
            const uint4* wp = &lds4[wbase0 ^ kq];
            uint4 xq[8];
            #pragma unroll
            for (int r = 0; r < 8; ++r) xq[r] = xp[8 * r];
            #pragma unroll
            for (int c = 0; c < 8; ++c) {
                uint4 wv = wp[8 * c];
                #pragma unroll
                for (int r = 0; r < 8; ++r) {
                    uint32_t a = acc[r][c];
                    a = __builtin_popcount(xq[r].x ^ wv.x) + a;
                    a = __builtin_popcount(xq[r].y ^ wv.y) + a;
                    a = __builtin_popcount(xq[r].z ^ wv.z) + a;
                    a = __builtin_popcount(xq[r].w ^ wv.w) + a;
                    acc[r][c] = a;
                }
            }
        }
    }
    float bv[8];
    #pragma unroll
    for (int c = 0; c < 8; ++c) bv[c] = bias[bcol + tx * 8 + c];
    #pragma unroll
    for (int r = 0; r < 8; ++r) {
        float vals[8];
        #pragma unroll
        for (int c = 0; c < 8; ++c)
            vals[c] = (float)(K_DIM - 2 * (int)acc[r][c]) + bv[c];
        float4* op = (float4*)(out + (size_t)(brow + ty * 8 + r) * O_DIM
                               + bcol + tx * 8);
        op[0] = make_float4(vals[0], vals[1], vals[2], vals[3]);
        op[1] = make_float4(vals[4], vals[5], vals[6], vals[7]);
    }
}

// ====================== launcher ============================================
extern "C" void kernel_launch(void* const* d_in, const int* in_sizes, int n_in,
                              void* d_out, int out_size, void* d_ws, size_t ws_size,
                              hipStream_t stream) {
    const float* X    = (const float*)d_in[0];
    const float* W    = (const float*)d_in[1];
    const float* bias = (const float*)d_in[2];
    float* out        = (float*)d_out;

    const size_t XB4 = (size_t)N_ROWS * K_DIM / 2;   // 16 MiB fp4 X
    const size_t WB4 = (size_t)O_DIM * K_DIM / 2;    //  8 MiB fp4 W

    if (ws_size >= XB4 + WB4) {
        uint8_t* XBlk = (uint8_t*)d_ws;
        uint8_t* WBlk = (uint8_t*)d_ws + XB4;

        convert_x_fp4<<<16384 / 4, 256, 0, stream>>>(X, XBlk);
        convert_w_fp4<<<8192 / 4, 256, 0, stream>>>(W, WBlk);
        fp4_gemm_kernel<<<(N_ROWS / 256) * (O_DIM / 128), 256, 0, stream>>>(
            XBlk, WBlk, bias, out);
    } else {
        uint64_t* Xb = (uint64_t*)d_ws;
        uint64_t* Wb = (uint64_t*)((uint8_t*)d_ws + (size_t)N_ROWS * KW * 8);
        pack_x_kernel<<<N_ROWS / 4, 256, 0, stream>>>(X, Xb);
        pack_w_kernel<<<16 * 64, 256, 0, stream>>>(W, Wb);
        xnor_gemm_kernel<<<(N_ROWS / 128) * (O_DIM / 128), 256, 0, stream>>>(
            (const uint8_t*)Xb, (const uint8_t*)Wb, bias, out);
    }
}

// Round 21
// 127.893 us; speedup vs baseline: 1.5184x; 1.0056x over previous
//
#include <hip/hip_runtime.h>
#include <stdint.h>

// BinarizeLinear inference: out = sign(X) @ sign(W) + bias
// Round 21: BK=128 steps (32 steps, was 64) -- halves the per-step fixed
// overhead (vmcnt+barrier+lgkm exposure, measured ~650cyc/step) that now
// dominates alongside the LDS port. Two half-clusters per step: half-1's
// ds_reads hide under half-0's MFMAs. 3-deep LDS (72 KiB, 2 blocks/CU),
// counted vmcnt(6). Converts unchanged from round 19/20. Exact math.

#define N_ROWS 8192
#define K_DIM  4096
#define O_DIM  4096
#define KW     64

typedef int   int4v    __attribute__((ext_vector_type(4)));
typedef int   int8v    __attribute__((ext_vector_type(8)));
typedef float float16v __attribute__((ext_vector_type(16)));

// fp4 operand: low 4 regs carry data, high 4 undef (FMT=fp4 ignores them)
__device__ __forceinline__ int8v mk8u(int4v x) {
    return __builtin_shufflevector(x, x, 0, 1, 2, 3, -1, -1, -1, -1);
}

// fp4 e2m1: +1.0 = 0x2, -1.0 = 0xA
__device__ __forceinline__ uint32_t nib4(float f) { return f > 0.0f ? 0x2u : 0xAu; }

// ====================== X -> fp4 blocked [G][kt][g][lane][16B] ==============
__global__ __launch_bounds__(256) void convert_x_fp4(
        const float* __restrict__ X, uint8_t* __restrict__ XB) {
    int u    = blockIdx.x * 4 + (threadIdx.x >> 6);   // [0, 16384)
    int lane = threadIdx.x & 63;
    int g = u & 7, kt = (u >> 3) & 63, G = u >> 9;
    int row = G * 256 + g * 32 + (lane & 31);
    int k0  = kt * 64 + (lane >> 5) * 32;
    const float4* src = (const float4*)(X + (size_t)row * K_DIM + k0);
    uint32_t ow[4];
    #pragma unroll
    for (int q = 0; q < 4; ++q) {
        float4 vA = src[2 * q];
        float4 vB = src[2 * q + 1];
        uint32_t b0 = nib4(vA.x) | (nib4(vA.y) << 4);
        uint32_t b1 = nib4(vA.z) | (nib4(vA.w) << 4);
        uint32_t b2 = nib4(vB.x) | (nib4(vB.y) << 4);
        uint32_t b3 = nib4(vB.z) | (nib4(vB.w) << 4);
        ow[q] = b0 | (b1 << 8) | (b2 << 16) | (b3 << 24);
    }
    int4v o; o.x = (int)ow[0]; o.y = (int)ow[1]; o.z = (int)ow[2]; o.w = (int)ow[3];
    *(int4v*)(XB + (size_t)u * 1024 + lane * 16) = o;
}

// ====================== W (f32 [in][out]) -> fp4 blocked ====================
__global__ __launch_bounds__(256) void convert_w_fp4(
        const float* __restrict__ W, uint8_t* __restrict__ WB) {
    int u    = blockIdx.x * 4 + (threadIdx.x >> 6);   // [0, 8192)
    int lane = threadIdx.x & 63;
    int g = u & 7, kt = (u >> 3) & 63, G = u >> 9;
    int o     = G * 256 + g * 32 + (lane & 31);
    int kbase = kt * 64 + (lane >> 5) * 32;
    const float* src = W + (size_t)kbase * O_DIM + o;
    uint32_t ow[4];
    #pragma unroll
    for (int q = 0; q < 4; ++q) {
        uint32_t v = 0;
        #pragma unroll
        for (int j = 0; j < 8; ++j) {
            float f = src[(size_t)(q * 8 + j) * O_DIM];
            v |= nib4(f) << (4 * j);
        }
        ow[q] = v;
    }
    int4v ov; ov.x = (int)ow[0]; ov.y = (int)ow[1]; ov.z = (int)ow[2]; ov.w = (int)ow[3];
    *(int4v*)(WB + (size_t)u * 1024 + lane * 16) = ov;
}

// ====================== 256x128 fp4 GEMM, BK=128, 3-deep pipeline ===========
#define MFMA4(a, b, c)                                                        \
    __builtin_amdgcn_mfma_scale_f32_32x32x64_f8f6f4(                          \
        (a), (b), (c), 4, 4, 0, 0x7F7F7F7F, 0, 0x7F7F7F7F)

__global__ __launch_bounds__(256, 2) void fp4_gemm_kernel(
        const uint8_t* __restrict__ XB, const uint8_t* __restrict__ WB,
        const float* __restrict__ bias, float* __restrict__ out) {
    __shared__ uint8_t lds[3 * 24576];   // 72 KiB: per buf [A 16KB | B 8KB]

    const int tid  = threadIdx.x;
    const int swzb = (blockIdx.x & 7) * 128 + (blockIdx.x >> 3);  // XCD swizzle
    const int brow = (swzb >> 5) * 256;
    const int bcol = (swzb & 31) * 128;

    const int lane = tid & 63;
    const int wid  = tid >> 6;
    const int wrow = (wid >> 1) * 128;   // 2 M-groups
    const int wcol = (wid & 1) * 64;     // 2 N-groups
    const int l31  = lane & 31;
    const int lh   = lane >> 5;

    const int ag0 = (wrow >> 5) * 1024 + lane * 16;          // A piece base
    const int bg0 = 16384 + (wcol >> 5) * 1024 + lane * 16;  // B piece base

    // [G][kt][g]: per-G bytes = 1<<19; step t = 16 KB (A) / our 4 KB (B)
    const uint8_t* Asrc = XB + ((size_t)(brow >> 8) << 19) + tid * 16;
    const uint8_t* Bsrc = WB + ((size_t)(bcol >> 8) << 19)
                             + ((bcol & 255) >> 5) * 1024 + tid * 16;

#define GSTAGE(buf, t)                                                        \
    {                                                                         \
        _Pragma("unroll")                                                     \
        for (int j = 0; j < 4; ++j) {                                         \
            __builtin_amdgcn_global_load_lds(                                 \
                (const __attribute__((address_space(1))) void*)               \
                    (Asrc + (size_t)(t) * 16384 + j * 4096),                  \
                (__attribute__((address_space(3))) void*)                     \
                    (lds + (buf) * 24576 + j * 4096 + tid * 16), 16, 0, 0);   \
        }                                                                     \
        _Pragma("unroll")                                                     \
        for (int h = 0; h < 2; ++h) {                                         \
            __builtin_amdgcn_global_load_lds(                                 \
                (const __attribute__((address_space(1))) void*)               \
                    (Bsrc + (size_t)(t) * 16384 + h * 8192),                  \
                (__attribute__((address_space(3))) void*)                     \
                    (lds + (buf) * 24576 + 16384 + h * 4096 + tid * 16),      \
                16, 0, 0);                                                    \
        }                                                                     \
    }

    // read fragments of k-half h from buffer buf into one named set
#define LOADH(A0, A1, A2, A3, B0, B1, buf, h)                                 \
    {                                                                         \
        const uint8_t* Ap = lds + (buf) * 24576 + (h) * 8192 + ag0;           \
        const uint8_t* Bp = lds + (buf) * 24576 + (h) * 4096 + bg0;           \
        A0 = mk8u(*(const int4v*)(Ap));                                       \
        A1 = mk8u(*(const int4v*)(Ap + 1024));                                \
        A2 = mk8u(*(const int4v*)(Ap + 2048));                                \
        A3 = mk8u(*(const int4v*)(Ap + 3072));                                \
        B0 = mk8u(*(const int4v*)(Bp));                                       \
        B1 = mk8u(*(const int4v*)(Bp + 1024));                                \
    }

#define MFMA8(A0, A1, A2, A3, B0, B1)                                         \
    {                                                                         \
        __builtin_amdgcn_s_setprio(1);                                        \
        c00 = MFMA4(A0, B0, c00);  c01 = MFMA4(A0, B1, c01);                  \
        c10 = MFMA4(A1, B0, c10);  c11 = MFMA4(A1, B1, c11);                  \
        c20 = MFMA4(A2, B0, c20);  c21 = MFMA4(A2, B1, c21);                  \
        c30 = MFMA4(A3, B0, c30);  c31 = MFMA4(A3, B1, c31);                  \
        __builtin_amdgcn_s_setprio(0);                                        \
    }

    // one BK=128 step: wait -> barrier -> stage(t+2) -> 2 half-clusters
#define STEP(bufc, bufs, t, LASTWAIT)                                         \
    {                                                                         \
        if (LASTWAIT) asm volatile("s_waitcnt vmcnt(0)" ::: "memory");        \
        else          asm volatile("s_waitcnt vmcnt(6)" ::: "memory");        \
        __builtin_amdgcn_s_barrier();                                         \
        if ((t) + 2 < 32) GSTAGE(bufs, (t) + 2);                              \
        LOADH(a0, a1, a2, a3, b0, b1, bufc, 0);                               \
        LOADH(na0, na1, na2, na3, nb0, nb1, bufc, 1);                         \
        MFMA8(a0, a1, a2, a3, b0, b1);                                        \
        MFMA8(na0, na1, na2, na3, nb0, nb1);                                  \
    }

    float16v c00 = 0, c01 = 0, c10 = 0, c11 = 0,
             c20 = 0, c21 = 0, c30 = 0, c31 = 0;
    int8v a0, a1, a2, a3, b0, b1;
    int8v na0, na1, na2, na3, nb0, nb1;

    // prologue: stage steps 0,1 (12 loads in flight)
    GSTAGE(0, 0);
    GSTAGE(1, 1);

    // t = 0..29 in 10 statically-indexed triples; tail t = 30 (buf 0), 31 (buf 1)
    for (int i = 0; i < 10; ++i) {
        const int t = 3 * i;
        STEP(0, 2, t,     false);
        STEP(1, 0, t + 1, false);
        STEP(2, 1, t + 2, false);
    }
    STEP(0, 2, 30, false);
    STEP(1, 0, 31, true);
#undef STEP
#undef MFMA8
#undef LOADH
#undef GSTAGE

    // epilogue: C/D map col=lane&31, row=(r&3)+8*(r>>2)+4*(lane>>5)
    float bv0 = bias[bcol + wcol + l31];
    float bv1 = bias[bcol + wcol + 32 + l31];
    const size_t obase = (size_t)(brow + wrow) * O_DIM + bcol + wcol;

#define CWRITE(cm, m, n, bv)                                                  \
    {                                                                         \
        _Pragma("unroll")                                                     \
        for (int r = 0; r < 16; ++r) {                                        \
            int rl = (r & 3) + 8 * (r >> 2) + 4 * lh;                         \
            out[obase + (size_t)((m) * 32 + rl) * O_DIM + (n) * 32 + l31] =   \
                cm[r] + (bv);                                                 \
        }                                                                     \
    }

    CWRITE(c00, 0, 0, bv0); CWRITE(c01, 0, 1, bv1);
    CWRITE(c10, 1, 0, bv0); CWRITE(c11, 1, 1, bv1);
    CWRITE(c20, 2, 0, bv0); CWRITE(c21, 2, 1, bv1);
    CWRITE(c30, 3, 0, bv0); CWRITE(c31, 3, 1, bv1);
#undef CWRITE
}

// ====================== popcount fallback (round-5, proven) =================
__global__ __launch_bounds__(256) void pack_x_kernel(
        const float* __restrict__ X, uint64_t* __restrict__ Xb) {
    int wave = (int)((blockIdx.x * blockDim.x + threadIdx.x) >> 6);
    int lane = threadIdx.x & 63;
    if (wave >= N_ROWS) return;
    const float* xr = X + (size_t)wave * K_DIM;
    uint64_t* xbr = Xb + (size_t)wave * KW;
    #pragma unroll 4
    for (int w = 0; w < KW; ++w) {
        float v = xr[w * 64 + lane];
        unsigned long long m = __ballot(v > 0.0f);
        if (lane == 0) xbr[w] = (uint64_t)m;
    }
}

__global__ __launch_bounds__(256) void pack_w_kernel(
        const float* __restrict__ W, uint64_t* __restrict__ Wb) {
    int oc = blockIdx.x & 15;
    int w  = blockIdx.x >> 4;
    int o  = oc * 256 + threadIdx.x;
    const float* wp = W + (size_t)(w * 64) * O_DIM + o;
    uint64_t word = 0;
    #pragma unroll 8
    for (int p = 0; p < 64; ++p) {
        float v = wp[(size_t)p * O_DIM];
        word |= (uint64_t)(v > 0.0f) << p;
    }
    Wb[(size_t)o * KW + w] = word;
}

__global__ __launch_bounds__(256) void xnor_gemm_kernel(
        const uint8_t* __restrict__ Xb, const uint8_t* __restrict__ Wb,
        const float* __restrict__ bias, float* __restrict__ out) {
    __shared__ uint4 lds4[2048];
    const int tid    = threadIdx.x;
    const int brow   = (blockIdx.x >> 5) * 128;
    const int bcol   = (blockIdx.x & 31) * 128;
    const int tx     = tid & 15;
    const int ty     = tid >> 4;
    const int widx   = tid >> 6;
    const int xbase0 = ty * 64 + (ty & 7);
    const int wbase0 = 1024 + tx * 64 + (tx & 7);
    uint32_t acc[8][8] = {};
    for (int kc = 0; kc < 4; ++kc) {
        __syncthreads();
        #pragma unroll
        for (int i = 0; i < 4; ++i) {
            int idx  = tid + 256 * i;
            int row  = idx >> 3;
            int srcc = (idx & 7) ^ ((idx >> 6) & 7);
            size_t goff = ((size_t)row << 9) + (kc << 7) + (srcc << 4);
            __builtin_amdgcn_global_load_lds(
                (const __attribute__((address_space(1))) void*)
                    (Xb + ((size_t)brow << 9) + goff),
                (__attribute__((address_space(3))) void*)
                    (lds4 + i * 256 + widx * 64), 16, 0, 0);
            __builtin_amdgcn_global_load_lds(
                (const __attribute__((address_space(1))) void*)
                    (Wb + ((size_t)bcol << 9) + goff),
                (__attribute__((address_space(3))) void*)
                    (lds4 + 1024 + i * 256 + widx * 64), 16, 0, 0);
        }
        asm volatile("s_waitcnt vmcnt(0)" ::: "memory");
        __syncthreads();
        for (int kq = 0; kq < 8; ++kq) {
            const uint4* xp = &lds4[xbase0 ^ kq];
            const uint4* wp = &lds4[wbase0 ^ kq];
            uint4 xq[8];
            #pragma unroll
            for (int r = 0; r < 8; ++r) xq[r] = xp[8 * r];
            #pragma unroll
            for (int c = 0; c < 8; ++c) {
                uint4 wv = wp[8 * c];
                #pragma unroll
                for (int r = 0; r < 8; ++r) {
                    uint32_t a = acc[r][c];
                    a = __builtin_popcount(xq[r].x ^ wv.x) + a;
                    a = __builtin_popcount(xq[r].y ^ wv.y) + a;
                    a = __builtin_popcount(xq[r].z ^ wv.z) + a;
                    a = __builtin_popcount(xq[r].w ^ wv.w) + a;
                    acc[r][c] = a;
                }
            }
        }
    }
    float bv[8];
    #pragma unroll
    for (int c = 0; c < 8; ++c) bv[c] = bias[bcol + tx * 8 + c];
    #pragma unroll
    for (int r = 0; r < 8; ++r) {
        float vals[8];
        #pragma unroll
        for (int c = 0; c < 8; ++c)
            vals[c] = (float)(K_DIM - 2 * (int)acc[r][c]) + bv[c];
        float4* op = (float4*)(out + (size_t)(brow + ty * 8 + r) * O_DIM
                               + bcol + tx * 8);
        op[0] = make_float4(vals[0], vals[1], vals[2], vals[3]);
        op[1] = make_float4(vals[4], vals[5], vals[6], vals[7]);
    }
}

// ====================== launcher ============================================
extern "C" void kernel_launch(void* const* d_in, const int* in_sizes, int n_in,
                              void* d_out, int out_size, void* d_ws, size_t ws_size,
                              hipStream_t stream) {
    const float* X    = (const float*)d_in[0];
    const float* W    = (const float*)d_in[1];
    const float* bias = (const float*)d_in[2];
    float* out        = (float*)d_out;

    const size_t XB4 = (size_t)N_ROWS * K_DIM / 2;   // 16 MiB fp4 X
    const size_t WB4 = (size_t)O_DIM * K_DIM / 2;    //  8 MiB fp4 W

    if (ws_size >= XB4 + WB4) {
        uint8_t* XBlk = (uint8_t*)d_ws;
        uint8_t* WBlk = (uint8_t*)d_ws + XB4;

        convert_x_fp4<<<16384 / 4, 256, 0, stream>>>(X, XBlk);
        convert_w_fp4<<<8192 / 4, 256, 0, stream>>>(W, WBlk);
        fp4_gemm_kernel<<<(N_ROWS / 256) * (O_DIM / 128), 256, 0, stream>>>(
            XBlk, WBlk, bias, out);
    } else {
        uint64_t* Xb = (uint64_t*)d_ws;
        uint64_t* Wb = (uint64_t*)((uint8_t*)d_ws + (size_t)N_ROWS * KW * 8);
        pack_x_kernel<<<N_ROWS / 4, 256, 0, stream>>>(X, Xb);
        pack_w_kernel<<<16 * 64, 256, 0, stream>>>(W, Wb);
        xnor_gemm_kernel<<<(N_ROWS / 128) * (O_DIM / 128), 256, 0, stream>>>(
            (const uint8_t*)Xb, (const uint8_t*)Wb, bias, out);
    }
}